// Round 1
// 40421.033 us; speedup vs baseline: 1.3851x; 1.3851x over previous
//
#include <hip/hip_runtime.h>
#include <stdint.h>

// ---------------------------------------------------------------------------
// Seq2seq LSTM autoencoder (T=4096, H=1024, L=2), fp32 end-to-end.
// Round 4: layer-pair fusion. The inter-layer dependence is skew-1, so the
// two encoder layers (and the two decoder layers) are co-scheduled in ONE
// 512-block kernel: blocks [0,256) run layer A, [256,512) run layer B, with
// B consuming A's tagged stream as it is produced (1-step pipeline skew).
// Only the enc->dec boundary is a true barrier (decoder needs encoder
// finals), so the schedule is: pair(enc L0, enc L1) -> pair(dec L0, dec L1)
// -> projection.  DEADLOCK-FREE by construction: layer-A blocks never wait
// on layer-B, so even with zero co-residency this degrades to the old
// serial behavior instead of hanging.
// Modes 1/3 now poll instream and own-slot CONCURRENTLY (poll_fill2) since
// the instream wait is real in the fused kernel.
// Scan geometry unchanged: 256 blocks/layer x 256 threads, 4 h-rows/block,
// fp32 weights in VGPRs, h streamed as self-validating tagged dword pairs.
// ---------------------------------------------------------------------------

#define T_STEPS 4096
#define H_DIM   1024
#define SLOT_DW 2048              // 1024 fp32 x 2 tagged dwords
#define NSLOT   4097
#define M1 0x7E57u
#define M2 0x7E58u
#define PANIC_ITERS (1u<<27)      // only reachable on a true deadlock

using u32 = uint32_t;

static __device__ __forceinline__ float sigf(float x){ return 1.0f/(1.0f+__expf(-x)); }
static __device__ __forceinline__ float tanh_f(float x){
  x = fminf(20.f, fmaxf(-20.f, x));
  float e = __expf(-2.f*x);
  return (1.f-e)/(1.f+e);
}

static __device__ __forceinline__ float4 untag4(const u32* q){
  float4 f;
  f.x=__uint_as_float((q[0]&0xFFFFu)|(q[1]<<16));
  f.y=__uint_as_float((q[2]&0xFFFFu)|(q[3]<<16));
  f.z=__uint_as_float((q[4]&0xFFFFu)|(q[5]<<16));
  f.w=__uint_as_float((q[6]&0xFFFFu)|(q[7]<<16));
  return f;
}

// Poll this thread's 8 dwords of a slot until tagged; deposit 4 fp32 into LDS.
static __device__ __forceinline__ void poll_fill(const u32* slot, u32 magic,
                                                 float* st, int wb, int tid,
                                                 u32* panic){
  const u32* q = slot + tid*8;
  u32 v[8]; u32 it=0;
  for(;;){
    #pragma unroll
    for(int m=0;m<8;m++) v[m]=__hip_atomic_load(q+m,__ATOMIC_RELAXED,__HIP_MEMORY_SCOPE_AGENT);
    bool ok = true;
    #pragma unroll
    for(int m=0;m<8;m++) ok = ok && ((v[m]>>16)==magic);
    if(ok) break;
    ++it;
    if((it & 255u)==0u){
      if(__hip_atomic_load(panic,__ATOMIC_RELAXED,__HIP_MEMORY_SCOPE_AGENT)==0xDEADBEEFu) break;
      if(it>PANIC_ITERS){ __hip_atomic_store(panic,0xDEADBEEFu,__ATOMIC_RELAXED,__HIP_MEMORY_SCOPE_AGENT); break; }
    }
    __builtin_amdgcn_s_sleep(4);
  }
  float4 f;
  f.x=__uint_as_float((v[0]&0xFFFFu)|(v[1]<<16));
  f.y=__uint_as_float((v[2]&0xFFFFu)|(v[3]<<16));
  f.z=__uint_as_float((v[4]&0xFFFFu)|(v[5]<<16));
  f.w=__uint_as_float((v[6]&0xFFFFu)|(v[7]<<16));
  *(float4*)(st+wb)=f;
}

// Concurrent dual-slot poll (modes 1/3): both 8-dword load sets stay in
// flight each retry, overlapping the instream and own-slot LLC round trips.
static __device__ __forceinline__ void poll_fill2(const u32* slotA, u32 mA,
                                                  const u32* slotB, u32 mB,
                                                  float* st, int wbA, int wbB,
                                                  int tid, u32* panic){
  const u32* qa = slotA + tid*8;
  const u32* qb = slotB + tid*8;
  u32 va[8], vb[8]; bool dA=false, dB=false; u32 it=0;
  for(;;){
    if(!dA){
      #pragma unroll
      for(int m=0;m<8;m++) va[m]=__hip_atomic_load(qa+m,__ATOMIC_RELAXED,__HIP_MEMORY_SCOPE_AGENT);
    }
    if(!dB){
      #pragma unroll
      for(int m=0;m<8;m++) vb[m]=__hip_atomic_load(qb+m,__ATOMIC_RELAXED,__HIP_MEMORY_SCOPE_AGENT);
    }
    if(!dA){
      bool ok=true;
      #pragma unroll
      for(int m=0;m<8;m++) ok = ok && ((va[m]>>16)==mA);
      dA=ok;
    }
    if(!dB){
      bool ok=true;
      #pragma unroll
      for(int m=0;m<8;m++) ok = ok && ((vb[m]>>16)==mB);
      dB=ok;
    }
    if(dA&&dB) break;
    ++it;
    if((it & 255u)==0u){
      if(__hip_atomic_load(panic,__ATOMIC_RELAXED,__HIP_MEMORY_SCOPE_AGENT)==0xDEADBEEFu) break;
      if(it>PANIC_ITERS){ __hip_atomic_store(panic,0xDEADBEEFu,__ATOMIC_RELAXED,__HIP_MEMORY_SCOPE_AGENT); break; }
    }
    __builtin_amdgcn_s_sleep(4);
  }
  float4 f;
  f.x=__uint_as_float((va[0]&0xFFFFu)|(va[1]<<16));
  f.y=__uint_as_float((va[2]&0xFFFFu)|(va[3]<<16));
  f.z=__uint_as_float((va[4]&0xFFFFu)|(va[5]<<16));
  f.w=__uint_as_float((va[6]&0xFFFFu)|(va[7]<<16));
  *(float4*)(st+wbA)=f;
  f.x=__uint_as_float((vb[0]&0xFFFFu)|(vb[1]<<16));
  f.y=__uint_as_float((vb[2]&0xFFFFu)|(vb[3]<<16));
  f.z=__uint_as_float((vb[4]&0xFFFFu)|(vb[5]<<16));
  f.w=__uint_as_float((vb[6]&0xFFFFu)|(vb[7]<<16));
  *(float4*)(st+wbB)=f;
}

static __device__ __forceinline__ void store_h(u32* slot, u32 magic, int e, float h){
  u32 b=__float_as_uint(h);
  __hip_atomic_store(slot+2*e,   (magic<<16)|(b&0xFFFFu), __ATOMIC_RELAXED,__HIP_MEMORY_SCOPE_AGENT);
  __hip_atomic_store(slot+2*e+1, (magic<<16)|(b>>16),     __ATOMIC_RELAXED,__HIP_MEMORY_SCOPE_AGENT);
}

// One LSTM layer over T steps (body; kb = this block's index within the layer).
// mode 0: input = raw x from global.    mode 1: input = tagged stream (m_in).
// mode 2: input = CONSTANT tagged slot (staged once; decoder L0 broadcast).
// mode 3: same as 1.
// Block kb owns h-rows hr0..hr0+3. Wave w = gate (i,f,g,o); lane l = one
// 32-col segment of the concatenated K=2048 [W_ih | W_hh] dot.
static __device__ __forceinline__ void lstm_scan_body(
    int kb, int tid, float* st, float* gl,
    const float* __restrict__ xin,
    const u32*  __restrict__ instream,
    u32*        __restrict__ own,
    u32 m_in, u32 m_own,
    const float* __restrict__ Wih, const float* __restrict__ Whh,
    const float* __restrict__ bih, const float* __restrict__ bhh,
    const float* __restrict__ c0,      // null -> zeros
    float*       __restrict__ cout,    // final c per row
    const u32*  __restrict__ h0slot,   // tagged slot holding h0; null -> zeros
    float*       __restrict__ fh_out,  // if non-null: write final h (enc L1)
    u32* __restrict__ panic,
    int mode)
{
  const int hr0=kb*4;
  const int w=tid>>6, l=tid&63;
  const int grow0=(w<<10)+hr0;             // first of 4 owned gate rows
  const int fb  = tid*4 + ((tid>>3)<<2);   // stage word base, IN part
  const int fbH = 1152+fb;                 // stage word base, H part
  const int sb  = l*36;                    // dot segment word base

  // fp32 weights in VGPRs: 4 rows x 32-col segment
  float wr0[32],wr1[32],wr2[32],wr3[32];
  {
    const float* srcb = (l<32) ? Wih + (size_t)grow0*H_DIM + l*32
                               : Whh + (size_t)grow0*H_DIM + (l-32)*32;
    #pragma unroll
    for(int i=0;i<8;i++){
      float4 a0=*(const float4*)(srcb + i*4);
      float4 a1=*(const float4*)(srcb + 1024 + i*4);
      float4 a2=*(const float4*)(srcb + 2048 + i*4);
      float4 a3=*(const float4*)(srcb + 3072 + i*4);
      wr0[4*i]=a0.x; wr0[4*i+1]=a0.y; wr0[4*i+2]=a0.z; wr0[4*i+3]=a0.w;
      wr1[4*i]=a1.x; wr1[4*i+1]=a1.y; wr1[4*i+2]=a1.z; wr1[4*i+3]=a1.w;
      wr2[4*i]=a2.x; wr2[4*i+1]=a2.y; wr2[4*i+2]=a2.z; wr2[4*i+3]=a2.w;
      wr3[4*i]=a3.x; wr3[4*i+1]=a3.y; wr3[4*i+2]=a3.z; wr3[4*i+3]=a3.w;
    }
  }

  float bI=0,bF=0,bG=0,bO=0,c_st=0.f,h_st=0.f;   // valid for tid<4
  if(tid<4){
    int o=hr0+tid;
    bI=bih[o]       + bhh[o];
    bF=bih[o+1024]  + bhh[o+1024];
    bG=bih[o+2048]  + bhh[o+2048];
    bO=bih[o+3072]  + bhh[o+3072];
    if(c0)     c_st=c0[o];
    if(h0slot) h_st=__uint_as_float((h0slot[2*o]&0xFFFFu)|(h0slot[2*o+1]<<16));
    store_h(own, m_own, o, h_st);              // own slot 0
  }
  if(mode==2){                                  // constant input: stage once
    float4 f = untag4(instream + tid*8);
    *(float4*)(st+fb)=f;
  }

  for(int t=0;t<T_STEPS;++t){
    if(mode==0){
      float4 xv=*(const float4*)(xin + (size_t)t*H_DIM + tid*4);
      *(float4*)(st+fb)=xv;
      poll_fill(own + (size_t)t*SLOT_DW, m_own, st, fbH, tid, panic);
    } else if(mode==2){
      poll_fill(own + (size_t)t*SLOT_DW, m_own, st, fbH, tid, panic);
    } else {
      poll_fill2(instream + (size_t)(t+1)*SLOT_DW, m_in,
                 own      + (size_t)t*SLOT_DW,     m_own,
                 st, fb, fbH, tid, panic);
    }
    __syncthreads();
    float p0=0.f,p1=0.f,p2=0.f,p3=0.f;
    #pragma unroll
    for(int i=0;i<8;i++){
      float4 s=*(const float4*)(st+sb+i*4);
      p0+=s.x*wr0[4*i]+s.y*wr0[4*i+1]+s.z*wr0[4*i+2]+s.w*wr0[4*i+3];
      p1+=s.x*wr1[4*i]+s.y*wr1[4*i+1]+s.z*wr1[4*i+2]+s.w*wr1[4*i+3];
      p2+=s.x*wr2[4*i]+s.y*wr2[4*i+1]+s.z*wr2[4*i+2]+s.w*wr2[4*i+3];
      p3+=s.x*wr3[4*i]+s.y*wr3[4*i+1]+s.z*wr3[4*i+2]+s.w*wr3[4*i+3];
    }
    #pragma unroll
    for(int off=32;off;off>>=1){
      p0+=__shfl_down(p0,off,64); p1+=__shfl_down(p1,off,64);
      p2+=__shfl_down(p2,off,64); p3+=__shfl_down(p3,off,64);
    }
    if(l==0){ gl[w*4+0]=p0; gl[w*4+1]=p1; gl[w*4+2]=p2; gl[w*4+3]=p3; }
    __syncthreads();
    if(tid<4){
      float gi=bI+gl[tid], gf=bF+gl[4+tid], gg=bG+gl[8+tid], go=bO+gl[12+tid];
      c_st = sigf(gf)*c_st + sigf(gi)*tanh_f(gg);
      h_st = sigf(go)*tanh_f(c_st);
      store_h(own + (size_t)(t+1)*SLOT_DW, m_own, hr0+tid, h_st);
      if(t==T_STEPS-1){
        cout[hr0+tid]=c_st;
        if(fh_out) fh_out[hr0+tid]=h_st;
      }
    }
    __syncthreads();
  }
}

// Fused layer pair: blocks [0,256) = layer A, [256,512) = layer B.
// B consumes A's stream with 1-step skew. A never waits on B, so the kernel
// cannot deadlock even if the blocks are not all co-resident.
__global__ __launch_bounds__(256,2) void lstm_scan_pair(
    const float* __restrict__ xinA,
    const u32*  __restrict__ insA, u32* __restrict__ ownA, u32 miA, u32 moA,
    const float* __restrict__ WihA, const float* __restrict__ WhhA,
    const float* __restrict__ bihA, const float* __restrict__ bhhA,
    const float* __restrict__ c0A, float* __restrict__ coutA,
    const u32*  __restrict__ h0A, float* __restrict__ fhA, int modeA,
    const u32*  __restrict__ insB, u32* __restrict__ ownB, u32 miB, u32 moB,
    const float* __restrict__ WihB, const float* __restrict__ WhhB,
    const float* __restrict__ bihB, const float* __restrict__ bhhB,
    const float* __restrict__ c0B, float* __restrict__ coutB,
    const u32*  __restrict__ h0B, float* __restrict__ fhB, int modeB,
    u32* __restrict__ panic)
{
  __shared__ __align__(16) float st[2304];
  __shared__ float gl[16];
  const int b=blockIdx.x, tid=threadIdx.x;
  if(b<256){
    lstm_scan_body(b, tid, st, gl, xinA, insA, ownA, miA, moA,
                   WihA, WhhA, bihA, bhhA, c0A, coutA, h0A, fhA, panic, modeA);
  } else {
    lstm_scan_body(b-256, tid, st, gl, nullptr, insB, ownB, miB, moB,
                   WihB, WhhB, bihB, bhhB, c0B, coutB, h0B, fhB, panic, modeB);
  }
}

// out[(4095-tp), o] = leaky( sum_k oW[o,k] * h1d[tp][k] + ob[o] )
__global__ __launch_bounds__(256) void proj_out(
    const u32* __restrict__ SB, const float* __restrict__ oW,
    const float* __restrict__ ob, float* __restrict__ out)
{
  __shared__ __align__(16) float hb[1024];
  const int tp=blockIdx.x, tid=threadIdx.x;
  float4 f = untag4(SB + (size_t)(tp+1)*SLOT_DW + tid*8);
  *(float4*)(hb + tid*4)=f;
  __syncthreads();
  #pragma unroll
  for(int j=0;j<4;j++){
    int o = tid + 256*j;
    const float* wr = oW + (size_t)o*H_DIM;
    float acc=0.f;
    for(int k=0;k<1024;k+=4){
      float4 wv=*(const float4*)(wr+k);
      acc += wv.x*hb[k]+wv.y*hb[k+1]+wv.z*hb[k+2]+wv.w*hb[k+3];
    }
    acc += ob[o];
    acc = acc>0.f ? acc : 0.01f*acc;
    out[(size_t)(4095-tp)*H_DIM + o]=acc;
  }
}

extern "C" void kernel_launch(void* const* d_in, const int* in_sizes, int n_in,
                              void* d_out, int out_size, void* d_ws, size_t ws_size,
                              hipStream_t stream) {
  const float* x    = (const float*)d_in[0];
  const float* eWih = (const float*)d_in[1];
  const float* eWhh = (const float*)d_in[2];
  const float* ebih = (const float*)d_in[3];
  const float* ebhh = (const float*)d_in[4];
  const float* dWih = (const float*)d_in[5];
  const float* dWhh = (const float*)d_in[6];
  const float* dbih = (const float*)d_in[7];
  const float* dbhh = (const float*)d_in[8];
  const float* oW   = (const float*)d_in[9];
  const float* ob   = (const float*)d_in[10];
  float* out = (float*)d_out;
  u32* ws = (u32*)d_ws;

  const size_t REGION = (size_t)NSLOT*SLOT_DW;
  u32*   SA    = ws;
  u32*   SB    = ws + REGION;
  float* CA    = (float*)(ws + 2*REGION);      // 2048 floats: enc c finals
  u32*   panic = ws + 2*REGION + 2048;
  const size_t LSTRIDE = (size_t)4096*1024;    // per-layer weight stride

  // clear tags + c buffer + panic
  size_t clr_bytes = (2*REGION + 2048 + 64)*4;
  hipMemsetAsync(d_ws, 0, clr_bytes, stream);

  // Phase 1: encoder L0 (mode 0, x -> SA/M1, zero init) co-resident with
  // encoder L1 (mode 1, SA/M1 -> SB/M1, zero init, writes final_hidden).
  lstm_scan_pair<<<512,256,0,stream>>>(
      x, nullptr, SA, 0u, M1,
      eWih, eWhh, ebih, ebhh,
      nullptr, CA, nullptr, nullptr, 0,
      SA, SB, M1, M1,
      eWih+LSTRIDE, eWhh+LSTRIDE, ebih+4096, ebhh+4096,
      nullptr, CA+1024, nullptr, out + (size_t)T_STEPS*H_DIM, 1,
      panic);

  // Phase 2: decoder L0 (mode 2, const input = final_hidden slot SB[4096],
  // stream SA reused with M2, init = enc L0 finals) co-resident with
  // decoder L1 (mode 3, SA/M2 -> SB/M2, init = enc L1 finals).
  lstm_scan_pair<<<512,256,0,stream>>>(
      nullptr, SB + (size_t)4096*SLOT_DW, SA, 0u, M2,
      dWih, dWhh, dbih, dbhh,
      CA, CA, SA + (size_t)4096*SLOT_DW, nullptr, 2,
      SA, SB, M2, M2,
      dWih+LSTRIDE, dWhh+LSTRIDE, dbih+4096, dbhh+4096,
      CA+1024, CA+1024, SB + (size_t)4096*SLOT_DW, nullptr, 3,
      panic);

  // projection + leaky ReLU + flip
  proj_out<<<4096,256,0,stream>>>(SB, oW, ob, out);
}